// Round 5
// baseline (323.514 us; speedup 1.0000x reference)
//
#include <hip/hip_runtime.h>
#include <math.h>

// SoftGate: gate-MLP (split-bf16 MFMA, pipelined) -> threshold -> compaction.
#define NB 8
#define NS 4096
#define ND 1024      // K (feature dim)
#define NDH 512      // N (hidden dim)
#define NTOK (NB*NS) // M = 32768
#define THRESH 0.1f
#define EPSV 1e-5f

using short8   = __attribute__((ext_vector_type(8)))  short;
using floatx16 = __attribute__((ext_vector_type(16))) float;
using floatv4  = __attribute__((ext_vector_type(4)))  float;  // native vec for nontemporal

__device__ __forceinline__ unsigned short f32_to_bf16_rne(float f) {
  union { float f; unsigned u; } v; v.f = f;
  unsigned r = v.u + 0x7fffu + ((v.u >> 16) & 1u);
  return (unsigned short)(r >> 16);
}
__device__ __forceinline__ float bf16_to_f32(unsigned short h) {
  union { unsigned u; float f; } v; v.u = ((unsigned)h) << 16;
  return v.f;
}

// ---------------------------------------------------------------------------
// K0: repack W1 into MFMA-B-fragment order, bf16 hi/lo by 1 KB chunk:
//   chunk(n32,k16): lane l holds n=n32*32+(l&31), k=k16*16+(l>>5)*8+j.
// Also zero-inits rowmax for k1's fused atomicMax.
// ---------------------------------------------------------------------------
__global__ __launch_bounds__(256)
void k0_prep(const float* __restrict__ W1, unsigned short* __restrict__ Wf,
             unsigned int* __restrict__ rowmax) {
  __shared__ float sw[16][513];
  const int t = threadIdx.x;
  const int k16 = blockIdx.x;                // 0..63
  if (k16 == 0 && t < NB) rowmax[t] = 0u;
#pragma unroll
  for (int i = 0; i < 8; ++i) {
    int flat = i * 256 + t;
    int r = flat >> 7, c4 = (flat & 127) << 2;
    *(float4*)&sw[r][c4] = *(const float4*)(W1 + (size_t)(k16 * 16 + r) * NDH + c4);
  }
  __syncthreads();
#pragma unroll
  for (int q = 0; q < 4; ++q) {
    int ss = q * 256 + t;
    int n32 = ss >> 6, lane = ss & 63;
    int n = n32 * 32 + (lane & 31);
    int kb = (lane >> 5) * 8;
    unsigned hi2[4], lo2[4];
#pragma unroll
    for (int j = 0; j < 4; ++j) {
      float w0 = sw[kb + 2 * j][n], w1 = sw[kb + 2 * j + 1][n];
      unsigned short h0 = f32_to_bf16_rne(w0), h1 = f32_to_bf16_rne(w1);
      unsigned short l0 = f32_to_bf16_rne(w0 - bf16_to_f32(h0));
      unsigned short l1 = f32_to_bf16_rne(w1 - bf16_to_f32(h1));
      hi2[j] = (unsigned)h0 | ((unsigned)h1 << 16);
      lo2[j] = (unsigned)l0 | ((unsigned)l1 << 16);
    }
    size_t cb = ((size_t)(n32 * 64 + k16) * 2) * 512 + (size_t)lane * 8;
    *(uint4*)(Wf + cb)       = make_uint4(hi2[0], hi2[1], hi2[2], hi2[3]);
    *(uint4*)(Wf + cb + 512) = make_uint4(lo2[0], lo2[1], lo2[2], lo2[3]);
  }
}

// ---------------------------------------------------------------------------
// K1: fused gate MLP. 3-term split-bf16 MFMA (hi·hi + lo·hi + hi·lo), fp32 acc.
// Pipeline: per iter -- barrier; issue B loads (consumed in order, progressive
// vmcnt); issue NEXT iter's x load (drains at next barrier, hidden behind the
// 48-MFMA phase); ds_read A; MFMA; convert prefetched x -> other LDS buffer.
// Tail fuses squash(tanh)+pad-zero+ysq store+atomicMax rowmax (exact max ->
// deterministic). BM=64 x N=512, BK=32; wave w owns cols [128w,128w+128).
// ---------------------------------------------------------------------------
__global__ __launch_bounds__(256, 2)
void k1_gemm(const float* __restrict__ x, const unsigned short* __restrict__ Wf,
             const float* __restrict__ b1, const float* __restrict__ W2,
             const int* __restrict__ pad, const float* __restrict__ b2,
             float* __restrict__ ysq, unsigned int* __restrict__ rowmax) {
  __shared__ __align__(16) unsigned short sx[2][2][64 * 40];  // [buf][hi/lo][m*40+k]
  __shared__ float red[4][64];

  const int tid = threadIdx.x;
  const int wave = tid >> 6, lane = tid & 63;
  const int l31 = lane & 31, h5 = lane >> 5;
  const int tok0 = blockIdx.x * 64;

  floatx16 acc[2][4];
#pragma unroll
  for (int mt = 0; mt < 2; ++mt)
#pragma unroll
    for (int nt = 0; nt < 4; ++nt)
#pragma unroll
      for (int r = 0; r < 16; ++r) acc[mt][nt][r] = 0.f;

  const int sm = tid >> 2;            // staging row 0..63
  const int sk = (tid & 3) * 8;       // staging k-offset {0,8,16,24}
  const float* xrow = x + (size_t)(tok0 + sm) * ND + sk;

  const unsigned short* wb[4];
#pragma unroll
  for (int nt = 0; nt < 4; ++nt)
    wb[nt] = Wf + (((size_t)(wave * 4 + nt) * 64) * 2) * 512 + (size_t)lane * 8;

  // prologue: stage x for it=0 into LDS buf 0
  {
    float4 xa = *(const float4*)xrow;
    float4 xb = *(const float4*)(xrow + 4);
    float v8[8] = {xa.x, xa.y, xa.z, xa.w, xb.x, xb.y, xb.z, xb.w};
    unsigned hp[4], lp[4];
#pragma unroll
    for (int j = 0; j < 4; ++j) {
      unsigned short h0 = f32_to_bf16_rne(v8[2 * j]);
      unsigned short h1 = f32_to_bf16_rne(v8[2 * j + 1]);
      unsigned short l0 = f32_to_bf16_rne(v8[2 * j] - bf16_to_f32(h0));
      unsigned short l1 = f32_to_bf16_rne(v8[2 * j + 1] - bf16_to_f32(h1));
      hp[j] = (unsigned)h0 | ((unsigned)h1 << 16);
      lp[j] = (unsigned)l0 | ((unsigned)l1 << 16);
    }
    *(uint4*)&sx[0][0][sm * 40 + sk] = make_uint4(hp[0], hp[1], hp[2], hp[3]);
    *(uint4*)&sx[0][1][sm * 40 + sk] = make_uint4(lp[0], lp[1], lp[2], lp[3]);
  }

  for (int it = 0; it < 32; ++it) {
    const int p = it & 1;
    __syncthreads();                  // LDS[p] ready; prev-iter prefetch drained
    // B fragments for THIS iter: issued now, consumed below in load order ->
    // compiler emits progressive vmcnt waits, first MFMA covers ~L2 latency.
    short8 bh[4][2], bl[4][2];
#pragma unroll
    for (int nt = 0; nt < 4; ++nt)
#pragma unroll
      for (int kh = 0; kh < 2; ++kh) {
        const unsigned short* q = wb[nt] + ((size_t)(2 * it + kh) * 2) * 512;
        bh[nt][kh] = *(const short8*)(q);
        bl[nt][kh] = *(const short8*)(q + 512);
      }
    // x prefetch for NEXT iter: ~900-cyc HBM latency hides behind MFMA phase
    float4 pxa, pxb;
    if (it < 31) {
      const float* xp = xrow + (it + 1) * 32;
      pxa = *(const float4*)xp;
      pxb = *(const float4*)(xp + 4);
    }
    // A fragments: lane holds x[tok=mt*32+l31][k = kh*16 + h5*8 + j]
    short8 ah[2][2], al[2][2];
#pragma unroll
    for (int mt = 0; mt < 2; ++mt)
#pragma unroll
      for (int kh = 0; kh < 2; ++kh) {
        ah[mt][kh] = *(const short8*)&sx[p][0][(mt * 32 + l31) * 40 + kh * 16 + h5 * 8];
        al[mt][kh] = *(const short8*)&sx[p][1][(mt * 32 + l31) * 40 + kh * 16 + h5 * 8];
      }
#pragma unroll
    for (int nt = 0; nt < 4; ++nt)
#pragma unroll
      for (int kh = 0; kh < 2; ++kh)
#pragma unroll
        for (int mt = 0; mt < 2; ++mt) {
          acc[mt][nt] = __builtin_amdgcn_mfma_f32_32x32x16_bf16(ah[mt][kh], bh[nt][kh], acc[mt][nt], 0, 0, 0);
          acc[mt][nt] = __builtin_amdgcn_mfma_f32_32x32x16_bf16(al[mt][kh], bh[nt][kh], acc[mt][nt], 0, 0, 0);
          acc[mt][nt] = __builtin_amdgcn_mfma_f32_32x32x16_bf16(ah[mt][kh], bl[nt][kh], acc[mt][nt], 0, 0, 0);
        }
    // convert prefetched x -> other LDS buffer (ready for next barrier)
    if (it < 31) {
      float v8[8] = {pxa.x, pxa.y, pxa.z, pxa.w, pxb.x, pxb.y, pxb.z, pxb.w};
      unsigned hp[4], lp[4];
#pragma unroll
      for (int j = 0; j < 4; ++j) {
        unsigned short h0 = f32_to_bf16_rne(v8[2 * j]);
        unsigned short h1 = f32_to_bf16_rne(v8[2 * j + 1]);
        unsigned short l0 = f32_to_bf16_rne(v8[2 * j] - bf16_to_f32(h0));
        unsigned short l1 = f32_to_bf16_rne(v8[2 * j + 1] - bf16_to_f32(h1));
        hp[j] = (unsigned)h0 | ((unsigned)h1 << 16);
        lp[j] = (unsigned)l0 | ((unsigned)l1 << 16);
      }
      *(uint4*)&sx[p ^ 1][0][sm * 40 + sk] = make_uint4(hp[0], hp[1], hp[2], hp[3]);
      *(uint4*)&sx[p ^ 1][1][sm * 40 + sk] = make_uint4(lp[0], lp[1], lp[2], lp[3]);
    }
  }

  // epilogue: relu(h+b1)*W2, shfl-reduce 32 col-lanes, LDS combine.
  // C/D layout (m74/m101): col=lane&31, row=(r&3)+8*(r>>2)+4*(lane>>5)
  float b1v[4], w2v[4];
#pragma unroll
  for (int nt = 0; nt < 4; ++nt) {
    const int n = wave * 128 + nt * 32 + l31;
    b1v[nt] = b1[n];
    w2v[nt] = W2[n];
  }
#pragma unroll
  for (int mt = 0; mt < 2; ++mt) {
    float pr[16];
#pragma unroll
    for (int r = 0; r < 16; ++r) pr[r] = 0.f;
#pragma unroll
    for (int nt = 0; nt < 4; ++nt)
#pragma unroll
      for (int r = 0; r < 16; ++r)
        pr[r] += fmaxf(acc[mt][nt][r] + b1v[nt], 0.f) * w2v[nt];
#pragma unroll
    for (int m = 1; m <= 16; m <<= 1)
#pragma unroll
      for (int r = 0; r < 16; ++r) pr[r] += __shfl_xor(pr[r], m, 64);
    if (l31 == 0) {
#pragma unroll
      for (int r = 0; r < 16; ++r) {
        int row = (r & 3) + 8 * (r >> 2) + 4 * h5;
        red[wave][mt * 32 + row] = pr[r];
      }
    }
  }
  __syncthreads();
  // fused k2a: squash, pad-zero, store ysq, exact row max via atomicMax
  if (tid < 64) {
    float s = red[0][tid] + red[1][tid] + red[2][tid] + red[3][tid];
    const int t = tok0 + tid;
    float yl = s + b2[0];
    float y = (1.f + tanhf(10.f * yl)) * 0.5f;
    if (pad[t]) y = 0.f;
    ysq[t] = y;
    float m = y;
#pragma unroll
    for (int o = 32; o >= 1; o >>= 1) m = fmaxf(m, __shfl_xor(m, o, 64));
    if (tid == 0) atomicMax(rowmax + (t >> 12), __float_as_uint(m));
  }
}

// ---------------------------------------------------------------------------
// K2b: per row -- adjust, threshold, stable shfl-scan compaction map, new_len,
// v_pad, and gate value packed by DEST index (gval) so k3 reads it directly.
// ---------------------------------------------------------------------------
__global__ __launch_bounds__(256)
void k2b(const float* __restrict__ ysq, const int* __restrict__ pad,
         const unsigned int* __restrict__ rowmax, float* __restrict__ gval,
         int* __restrict__ src_of_dest, int* __restrict__ new_len,
         float* __restrict__ vpad_out) {
  __shared__ int ssum[4];
  const int b = blockIdx.x, tid = threadIdx.x;
  const int lane = tid & 63, wv = tid >> 6;
  const int base = b * NS, s0 = tid * 16;
  const float adj = fmaxf(EPSV + THRESH - __uint_as_float(rowmax[b]), 0.f);

  float yv[16];
  unsigned km = 0;
  int cnt = 0;
#pragma unroll
  for (int i = 0; i < 16; ++i) {
    int s = s0 + i;
    float yf = ysq[base + s] + adj;
    yv[i] = yf;
    bool keep = (yf > THRESH) && !pad[base + s];
    if (keep) { km |= (1u << i); ++cnt; }
  }
  // wave inclusive scan of per-thread counts
  int inc = cnt;
#pragma unroll
  for (int o = 1; o < 64; o <<= 1) {
    int tmp = __shfl_up(inc, o, 64);
    if (lane >= o) inc += tmp;
  }
  if (lane == 63) ssum[wv] = inc;
  __syncthreads();
  int wpre = 0;
  for (int w = 0; w < wv; ++w) wpre += ssum[w];
  const int total = ssum[0] + ssum[1] + ssum[2] + ssum[3];
  int off = wpre + inc - cnt;   // exclusive offset, stable order
#pragma unroll
  for (int i = 0; i < 16; ++i) {
    int s = s0 + i;
    if ((km >> i) & 1u) {
      src_of_dest[base + off] = s;
      gval[base + off] = yv[i];
      ++off;
    }
    vpad_out[base + s] = (s >= total) ? 1.f : 0.f;
  }
  if (tid == 0) new_len[b] = total;
}

// ---------------------------------------------------------------------------
// K3: 16 output slots per block (2048 blocks): v = x[src]*gval or zeros.
// Nontemporal stores (native ext_vector float4) -- v is written once.
// ---------------------------------------------------------------------------
__global__ __launch_bounds__(256)
void k3_gather(const float* __restrict__ x, const float* __restrict__ gval,
               const int* __restrict__ src_of_dest, const int* __restrict__ new_len,
               float* __restrict__ v) {
  const int slot0 = blockIdx.x * 16;
  const int b = slot0 >> 12;            // 16 | 4096 -> same row for all 16
  const int nl = new_len[b];
  const int tid = threadIdx.x;
#pragma unroll
  for (int i = 0; i < 16; ++i) {
    const int slot = slot0 + i;
    const int dest = slot & (NS - 1);
    floatv4* vo = (floatv4*)(v + (size_t)slot * ND);
    floatv4 r;
    if (dest < nl) {
      const int src = src_of_dest[slot];
      const float g = gval[slot];
      floatv4 xv = ((const floatv4*)(x + ((size_t)b * NS + src) * ND))[tid];
      r = xv * g;
    } else {
      r = (floatv4)(0.f);
    }
    __builtin_nontemporal_store(r, vo + tid);
  }
}

extern "C" void kernel_launch(void* const* d_in, const int* in_sizes, int n_in,
                              void* d_out, int out_size, void* d_ws, size_t ws_size,
                              hipStream_t stream) {
  const float* x   = (const float*)d_in[0];
  const int*   pad = (const int*)d_in[1];
  const float* W1  = (const float*)d_in[2];
  const float* b1  = (const float*)d_in[3];
  const float* W2  = (const float*)d_in[4];
  const float* b2  = (const float*)d_in[5];

  float* v    = (float*)d_out;                 // [8,4096,1024]
  float* vpad = v + (size_t)NTOK * ND;         // [8,4096]

  // Wf scratch inside d_out's v region: k1 reads it, k3 later overwrites all
  // of v (same-stream ordering makes this safe, incl. rocprof replay).
  unsigned short* Wf = (unsigned short*)(v + 24000000);  // 2 MB packed W

  // d_ws (~384 KB): ysq, gval, src map, new_len, rowmax
  float* ysq  = (float*)d_ws;                  // NTOK
  float* gval = ysq + NTOK;                    // NTOK
  int* src    = (int*)(gval + NTOK);           // NTOK
  int* nlen   = src + NTOK;                    // NB
  unsigned int* rowmax = (unsigned int*)(nlen + NB);  // NB

  k0_prep<<<64, 256, 0, stream>>>(W1, Wf, rowmax);
  k1_gemm<<<NTOK / 64, 256, 0, stream>>>(x, Wf, b1, W2, pad, b2, ysq, rowmax);
  k2b<<<NB, 256, 0, stream>>>(ysq, pad, rowmax, gval, src, nlen, vpad);
  k3_gather<<<NTOK / 16, 256, 0, stream>>>(x, gval, src, nlen, v);
}

// Round 6
// 320.065 us; speedup vs baseline: 1.0108x; 1.0108x over previous
//
#include <hip/hip_runtime.h>
#include <math.h>

// SoftGate: gate-MLP (split-bf16 MFMA, pipelined) -> threshold -> compaction.
#define NB 8
#define NS 4096
#define ND 1024      // K (feature dim)
#define NDH 512      // N (hidden dim)
#define NTOK (NB*NS) // M = 32768
#define THRESH 0.1f
#define EPSV 1e-5f

using short8   = __attribute__((ext_vector_type(8)))  short;
using floatx16 = __attribute__((ext_vector_type(16))) float;
using floatv4  = __attribute__((ext_vector_type(4)))  float;  // native vec for nontemporal

__device__ __forceinline__ unsigned short f32_to_bf16_rne(float f) {
  union { float f; unsigned u; } v; v.f = f;
  unsigned r = v.u + 0x7fffu + ((v.u >> 16) & 1u);
  return (unsigned short)(r >> 16);
}
__device__ __forceinline__ float bf16_to_f32(unsigned short h) {
  union { unsigned u; float f; } v; v.u = ((unsigned)h) << 16;
  return v.f;
}

// ---------------------------------------------------------------------------
// K0: repack W1 into MFMA-B-fragment order, bf16 hi/lo by 1 KB chunk:
//   chunk(n32,k16): lane l holds n=n32*32+(l&31), k=k16*16+(l>>5)*8+j.
// Also zero-inits rowmax for k1's fused atomicMax.
// ---------------------------------------------------------------------------
__global__ __launch_bounds__(256)
void k0_prep(const float* __restrict__ W1, unsigned short* __restrict__ Wf,
             unsigned int* __restrict__ rowmax) {
  __shared__ float sw[16][513];
  const int t = threadIdx.x;
  const int k16 = blockIdx.x;                // 0..63
  if (k16 == 0 && t < NB) rowmax[t] = 0u;
#pragma unroll
  for (int i = 0; i < 8; ++i) {
    int flat = i * 256 + t;
    int r = flat >> 7, c4 = (flat & 127) << 2;
    *(float4*)&sw[r][c4] = *(const float4*)(W1 + (size_t)(k16 * 16 + r) * NDH + c4);
  }
  __syncthreads();
#pragma unroll
  for (int q = 0; q < 4; ++q) {
    int ss = q * 256 + t;
    int n32 = ss >> 6, lane = ss & 63;
    int n = n32 * 32 + (lane & 31);
    int kb = (lane >> 5) * 8;
    unsigned hi2[4], lo2[4];
#pragma unroll
    for (int j = 0; j < 4; ++j) {
      float w0 = sw[kb + 2 * j][n], w1 = sw[kb + 2 * j + 1][n];
      unsigned short h0 = f32_to_bf16_rne(w0), h1 = f32_to_bf16_rne(w1);
      unsigned short l0 = f32_to_bf16_rne(w0 - bf16_to_f32(h0));
      unsigned short l1 = f32_to_bf16_rne(w1 - bf16_to_f32(h1));
      hi2[j] = (unsigned)h0 | ((unsigned)h1 << 16);
      lo2[j] = (unsigned)l0 | ((unsigned)l1 << 16);
    }
    size_t cb = ((size_t)(n32 * 64 + k16) * 2) * 512 + (size_t)lane * 8;
    *(uint4*)(Wf + cb)       = make_uint4(hi2[0], hi2[1], hi2[2], hi2[3]);
    *(uint4*)(Wf + cb + 512) = make_uint4(lo2[0], lo2[1], lo2[2], lo2[3]);
  }
}

// ---------------------------------------------------------------------------
// K1: fused gate MLP. 3-term split-bf16 MFMA (hi·hi + lo·hi + hi·lo), fp32 acc.
// MFMA issue order is TERM-OUTER: for each kh, all 8 independent (mt,nt)
// MFMAs of one term before the next term touches the same accumulator --
// reuse distance 8 MFMAs (~256 cyc) > dependent-issue latency, so the matrix
// pipe never stalls on acc RAW. Per-acc accumulation order is unchanged
// (kh0: hh,lh,hl; kh1: hh,lh,hl) -> bit-identical to R5.
// Tail fuses squash(tanh)+pad-zero+ysq store+atomicMax rowmax (exact max ->
// deterministic). BM=64 x N=512, BK=32; wave w owns cols [128w,128w+128).
// ---------------------------------------------------------------------------
__global__ __launch_bounds__(256, 2)
void k1_gemm(const float* __restrict__ x, const unsigned short* __restrict__ Wf,
             const float* __restrict__ b1, const float* __restrict__ W2,
             const int* __restrict__ pad, const float* __restrict__ b2,
             float* __restrict__ ysq, unsigned int* __restrict__ rowmax) {
  __shared__ __align__(16) unsigned short sx[2][2][64 * 40];  // [buf][hi/lo][m*40+k]
  __shared__ float red[4][64];

  const int tid = threadIdx.x;
  const int wave = tid >> 6, lane = tid & 63;
  const int l31 = lane & 31, h5 = lane >> 5;
  const int tok0 = blockIdx.x * 64;

  floatx16 acc[2][4];
#pragma unroll
  for (int mt = 0; mt < 2; ++mt)
#pragma unroll
    for (int nt = 0; nt < 4; ++nt)
#pragma unroll
      for (int r = 0; r < 16; ++r) acc[mt][nt][r] = 0.f;

  const int sm = tid >> 2;            // staging row 0..63
  const int sk = (tid & 3) * 8;       // staging k-offset {0,8,16,24}
  const float* xrow = x + (size_t)(tok0 + sm) * ND + sk;

  const unsigned short* wb[4];
#pragma unroll
  for (int nt = 0; nt < 4; ++nt)
    wb[nt] = Wf + (((size_t)(wave * 4 + nt) * 64) * 2) * 512 + (size_t)lane * 8;

  // prologue: stage x for it=0 into LDS buf 0
  {
    float4 xa = *(const float4*)xrow;
    float4 xb = *(const float4*)(xrow + 4);
    float v8[8] = {xa.x, xa.y, xa.z, xa.w, xb.x, xb.y, xb.z, xb.w};
    unsigned hp[4], lp[4];
#pragma unroll
    for (int j = 0; j < 4; ++j) {
      unsigned short h0 = f32_to_bf16_rne(v8[2 * j]);
      unsigned short h1 = f32_to_bf16_rne(v8[2 * j + 1]);
      unsigned short l0 = f32_to_bf16_rne(v8[2 * j] - bf16_to_f32(h0));
      unsigned short l1 = f32_to_bf16_rne(v8[2 * j + 1] - bf16_to_f32(h1));
      hp[j] = (unsigned)h0 | ((unsigned)h1 << 16);
      lp[j] = (unsigned)l0 | ((unsigned)l1 << 16);
    }
    *(uint4*)&sx[0][0][sm * 40 + sk] = make_uint4(hp[0], hp[1], hp[2], hp[3]);
    *(uint4*)&sx[0][1][sm * 40 + sk] = make_uint4(lp[0], lp[1], lp[2], lp[3]);
  }

  for (int it = 0; it < 32; ++it) {
    const int p = it & 1;
    __syncthreads();                  // LDS[p] ready; prev-iter prefetch drained
    // B fragments for THIS iter: issued now, consumed below in load order ->
    // compiler emits progressive vmcnt waits, first MFMA covers ~L2 latency.
    short8 bh[4][2], bl[4][2];
#pragma unroll
    for (int nt = 0; nt < 4; ++nt)
#pragma unroll
      for (int kh = 0; kh < 2; ++kh) {
        const unsigned short* q = wb[nt] + ((size_t)(2 * it + kh) * 2) * 512;
        bh[nt][kh] = *(const short8*)(q);
        bl[nt][kh] = *(const short8*)(q + 512);
      }
    // x prefetch for NEXT iter: ~900-cyc HBM latency hides behind MFMA phase
    float4 pxa, pxb;
    if (it < 31) {
      const float* xp = xrow + (it + 1) * 32;
      pxa = *(const float4*)xp;
      pxb = *(const float4*)(xp + 4);
    }
    // A fragments: lane holds x[tok=mt*32+l31][k = kh*16 + h5*8 + j]
    short8 ah[2][2], al[2][2];
#pragma unroll
    for (int mt = 0; mt < 2; ++mt)
#pragma unroll
      for (int kh = 0; kh < 2; ++kh) {
        ah[mt][kh] = *(const short8*)&sx[p][0][(mt * 32 + l31) * 40 + kh * 16 + h5 * 8];
        al[mt][kh] = *(const short8*)&sx[p][1][(mt * 32 + l31) * 40 + kh * 16 + h5 * 8];
      }
    // term-outer MFMA issue: 8 independent accs between same-acc reuse
#pragma unroll
    for (int kh = 0; kh < 2; ++kh) {
#pragma unroll
      for (int nt = 0; nt < 4; ++nt)
#pragma unroll
        for (int mt = 0; mt < 2; ++mt)
          acc[mt][nt] = __builtin_amdgcn_mfma_f32_32x32x16_bf16(ah[mt][kh], bh[nt][kh], acc[mt][nt], 0, 0, 0);
#pragma unroll
      for (int nt = 0; nt < 4; ++nt)
#pragma unroll
        for (int mt = 0; mt < 2; ++mt)
          acc[mt][nt] = __builtin_amdgcn_mfma_f32_32x32x16_bf16(al[mt][kh], bh[nt][kh], acc[mt][nt], 0, 0, 0);
#pragma unroll
      for (int nt = 0; nt < 4; ++nt)
#pragma unroll
        for (int mt = 0; mt < 2; ++mt)
          acc[mt][nt] = __builtin_amdgcn_mfma_f32_32x32x16_bf16(ah[mt][kh], bl[nt][kh], acc[mt][nt], 0, 0, 0);
    }
    // convert prefetched x -> other LDS buffer (ready for next barrier)
    if (it < 31) {
      float v8[8] = {pxa.x, pxa.y, pxa.z, pxa.w, pxb.x, pxb.y, pxb.z, pxb.w};
      unsigned hp[4], lp[4];
#pragma unroll
      for (int j = 0; j < 4; ++j) {
        unsigned short h0 = f32_to_bf16_rne(v8[2 * j]);
        unsigned short h1 = f32_to_bf16_rne(v8[2 * j + 1]);
        unsigned short l0 = f32_to_bf16_rne(v8[2 * j] - bf16_to_f32(h0));
        unsigned short l1 = f32_to_bf16_rne(v8[2 * j + 1] - bf16_to_f32(h1));
        hp[j] = (unsigned)h0 | ((unsigned)h1 << 16);
        lp[j] = (unsigned)l0 | ((unsigned)l1 << 16);
      }
      *(uint4*)&sx[p ^ 1][0][sm * 40 + sk] = make_uint4(hp[0], hp[1], hp[2], hp[3]);
      *(uint4*)&sx[p ^ 1][1][sm * 40 + sk] = make_uint4(lp[0], lp[1], lp[2], lp[3]);
    }
  }

  // epilogue: relu(h+b1)*W2, shfl-reduce 32 col-lanes, LDS combine.
  // C/D layout (m74/m101): col=lane&31, row=(r&3)+8*(r>>2)+4*(lane>>5)
  float b1v[4], w2v[4];
#pragma unroll
  for (int nt = 0; nt < 4; ++nt) {
    const int n = wave * 128 + nt * 32 + l31;
    b1v[nt] = b1[n];
    w2v[nt] = W2[n];
  }
#pragma unroll
  for (int mt = 0; mt < 2; ++mt) {
    float pr[16];
#pragma unroll
    for (int r = 0; r < 16; ++r) pr[r] = 0.f;
#pragma unroll
    for (int nt = 0; nt < 4; ++nt)
#pragma unroll
      for (int r = 0; r < 16; ++r)
        pr[r] += fmaxf(acc[mt][nt][r] + b1v[nt], 0.f) * w2v[nt];
#pragma unroll
    for (int m = 1; m <= 16; m <<= 1)
#pragma unroll
      for (int r = 0; r < 16; ++r) pr[r] += __shfl_xor(pr[r], m, 64);
    if (l31 == 0) {
#pragma unroll
      for (int r = 0; r < 16; ++r) {
        int row = (r & 3) + 8 * (r >> 2) + 4 * h5;
        red[wave][mt * 32 + row] = pr[r];
      }
    }
  }
  __syncthreads();
  // fused k2a: squash, pad-zero, store ysq, exact row max via atomicMax
  if (tid < 64) {
    float s = red[0][tid] + red[1][tid] + red[2][tid] + red[3][tid];
    const int t = tok0 + tid;
    float yl = s + b2[0];
    float y = (1.f + tanhf(10.f * yl)) * 0.5f;
    if (pad[t]) y = 0.f;
    ysq[t] = y;
    float m = y;
#pragma unroll
    for (int o = 32; o >= 1; o >>= 1) m = fmaxf(m, __shfl_xor(m, o, 64));
    if (tid == 0) atomicMax(rowmax + (t >> 12), __float_as_uint(m));
  }
}

// ---------------------------------------------------------------------------
// K2b: per row -- adjust, threshold, stable shfl-scan compaction map, new_len,
// v_pad, and gate value packed by DEST index (gval) so k3 reads it directly.
// ---------------------------------------------------------------------------
__global__ __launch_bounds__(256)
void k2b(const float* __restrict__ ysq, const int* __restrict__ pad,
         const unsigned int* __restrict__ rowmax, float* __restrict__ gval,
         int* __restrict__ src_of_dest, int* __restrict__ new_len,
         float* __restrict__ vpad_out) {
  __shared__ int ssum[4];
  const int b = blockIdx.x, tid = threadIdx.x;
  const int lane = tid & 63, wv = tid >> 6;
  const int base = b * NS, s0 = tid * 16;
  const float adj = fmaxf(EPSV + THRESH - __uint_as_float(rowmax[b]), 0.f);

  float yv[16];
  unsigned km = 0;
  int cnt = 0;
#pragma unroll
  for (int i = 0; i < 16; ++i) {
    int s = s0 + i;
    float yf = ysq[base + s] + adj;
    yv[i] = yf;
    bool keep = (yf > THRESH) && !pad[base + s];
    if (keep) { km |= (1u << i); ++cnt; }
  }
  // wave inclusive scan of per-thread counts
  int inc = cnt;
#pragma unroll
  for (int o = 1; o < 64; o <<= 1) {
    int tmp = __shfl_up(inc, o, 64);
    if (lane >= o) inc += tmp;
  }
  if (lane == 63) ssum[wv] = inc;
  __syncthreads();
  int wpre = 0;
  for (int w = 0; w < wv; ++w) wpre += ssum[w];
  const int total = ssum[0] + ssum[1] + ssum[2] + ssum[3];
  int off = wpre + inc - cnt;   // exclusive offset, stable order
#pragma unroll
  for (int i = 0; i < 16; ++i) {
    int s = s0 + i;
    if ((km >> i) & 1u) {
      src_of_dest[base + off] = s;
      gval[base + off] = yv[i];
      ++off;
    }
    vpad_out[base + s] = (s >= total) ? 1.f : 0.f;
  }
  if (tid == 0) new_len[b] = total;
}

// ---------------------------------------------------------------------------
// K3: 16 output slots per block (2048 blocks): v = x[src]*gval or zeros.
// Nontemporal stores (native ext_vector float4) -- v is written once.
// ---------------------------------------------------------------------------
__global__ __launch_bounds__(256)
void k3_gather(const float* __restrict__ x, const float* __restrict__ gval,
               const int* __restrict__ src_of_dest, const int* __restrict__ new_len,
               float* __restrict__ v) {
  const int slot0 = blockIdx.x * 16;
  const int b = slot0 >> 12;            // 16 | 4096 -> same row for all 16
  const int nl = new_len[b];
  const int tid = threadIdx.x;
#pragma unroll
  for (int i = 0; i < 16; ++i) {
    const int slot = slot0 + i;
    const int dest = slot & (NS - 1);
    floatv4* vo = (floatv4*)(v + (size_t)slot * ND);
    floatv4 r;
    if (dest < nl) {
      const int src = src_of_dest[slot];
      const float g = gval[slot];
      floatv4 xv = ((const floatv4*)(x + ((size_t)b * NS + src) * ND))[tid];
      r = xv * g;
    } else {
      r = (floatv4)(0.f);
    }
    __builtin_nontemporal_store(r, vo + tid);
  }
}

extern "C" void kernel_launch(void* const* d_in, const int* in_sizes, int n_in,
                              void* d_out, int out_size, void* d_ws, size_t ws_size,
                              hipStream_t stream) {
  const float* x   = (const float*)d_in[0];
  const int*   pad = (const int*)d_in[1];
  const float* W1  = (const float*)d_in[2];
  const float* b1  = (const float*)d_in[3];
  const float* W2  = (const float*)d_in[4];
  const float* b2  = (const float*)d_in[5];

  float* v    = (float*)d_out;                 // [8,4096,1024]
  float* vpad = v + (size_t)NTOK * ND;         // [8,4096]

  // Wf scratch inside d_out's v region: k1 reads it, k3 later overwrites all
  // of v (same-stream ordering makes this safe, incl. rocprof replay).
  unsigned short* Wf = (unsigned short*)(v + 24000000);  // 2 MB packed W

  // d_ws (~384 KB): ysq, gval, src map, new_len, rowmax
  float* ysq  = (float*)d_ws;                  // NTOK
  float* gval = ysq + NTOK;                    // NTOK
  int* src    = (int*)(gval + NTOK);           // NTOK
  int* nlen   = src + NTOK;                    // NB
  unsigned int* rowmax = (unsigned int*)(nlen + NB);  // NB

  k0_prep<<<64, 256, 0, stream>>>(W1, Wf, rowmax);
  k1_gemm<<<NTOK / 64, 256, 0, stream>>>(x, Wf, b1, W2, pad, b2, ysq, rowmax);
  k2b<<<NB, 256, 0, stream>>>(ysq, pad, rowmax, gval, src, nlen, vpad);
  k3_gather<<<NTOK / 16, 256, 0, stream>>>(x, gval, src, nlen, v);
}